// Round 3
// baseline (23499.802 us; speedup 1.0000x reference)
//
#include <hip/hip_runtime.h>
#include <math.h>

#define NN 10000
#define EE 320000
#define INC 64
#define HH 128
#define G4 512

typedef short short8 __attribute__((ext_vector_type(8)));
typedef float f32x4 __attribute__((ext_vector_type(4)));

__device__ __forceinline__ float sigm(float x) { return 1.f / (1.f + __expf(-x)); }
__device__ __forceinline__ float tanh_fast(float x) { return 1.f - 2.f / (1.f + __expf(2.f * x)); }

// fp32 -> bf16 round-to-nearest-even
__device__ __forceinline__ unsigned short f2bf(float f) {
    unsigned u = __float_as_uint(f);
    unsigned r = u + 0x7FFFu + ((u >> 16) & 1u);
    return (unsigned short)(r >> 16);
}

// ---------------- init: zero bn stats (both layers) ----------------
__global__ void k_init(float* stats) {
    int i = blockIdx.x * 256 + threadIdx.x;
    if (i < 512) stats[i] = 0.f;
}

// ---------------- broadcast bias into agg buffer ----------------
__global__ void k_bias_bcast(float* __restrict__ out, const float* __restrict__ b) {
    int i = blockIdx.x * 256 + threadIdx.x;
    if (i < NN * HH) out[i] = b[i & (HH - 1)];
}

// ---------------- C[M,128] = A[M,K] @ B[K,128], K in {64,128} ----------------
__global__ __launch_bounds__(256) void k_gemm_ab(const float* __restrict__ A,
                                                 const float* __restrict__ B,
                                                 float* __restrict__ C,
                                                 int M, int K, int kshift) {
    __shared__ float Alds[32 * 129];
    int tid = threadIdx.x;
    int m0 = blockIdx.x * 32;
    for (int i = tid; i < 32 * K; i += 256) {
        int r = i >> kshift;
        int k = i & (K - 1);
        int m = m0 + r;
        Alds[r * 129 + k] = (m < M) ? A[m * K + k] : 0.f;
    }
    __syncthreads();
    int r = tid >> 3;
    int cg = (tid & 7) * 16;
    float acc[16];
#pragma unroll
    for (int j = 0; j < 16; j++) acc[j] = 0.f;
#pragma unroll 4
    for (int k = 0; k < K; ++k) {
        float a = Alds[r * 129 + k];
        const float4* Brow = (const float4*)(B + k * HH + cg);
        float4 b0 = Brow[0], b1 = Brow[1], b2 = Brow[2], b3 = Brow[3];
        acc[0]  = fmaf(a, b0.x, acc[0]);  acc[1]  = fmaf(a, b0.y, acc[1]);
        acc[2]  = fmaf(a, b0.z, acc[2]);  acc[3]  = fmaf(a, b0.w, acc[3]);
        acc[4]  = fmaf(a, b1.x, acc[4]);  acc[5]  = fmaf(a, b1.y, acc[5]);
        acc[6]  = fmaf(a, b1.z, acc[6]);  acc[7]  = fmaf(a, b1.w, acc[7]);
        acc[8]  = fmaf(a, b2.x, acc[8]);  acc[9]  = fmaf(a, b2.y, acc[9]);
        acc[10] = fmaf(a, b2.z, acc[10]); acc[11] = fmaf(a, b2.w, acc[11]);
        acc[12] = fmaf(a, b3.x, acc[12]); acc[13] = fmaf(a, b3.y, acc[13]);
        acc[14] = fmaf(a, b3.z, acc[14]); acc[15] = fmaf(a, b3.w, acc[15]);
    }
    int m = m0 + r;
    if (m < M) {
        float4* Crow = (float4*)(C + m * HH + cg);
        Crow[0] = make_float4(acc[0], acc[1], acc[2], acc[3]);
        Crow[1] = make_float4(acc[4], acc[5], acc[6], acc[7]);
        Crow[2] = make_float4(acc[8], acc[9], acc[10], acc[11]);
        Crow[3] = make_float4(acc[12], acc[13], acc[14], acc[15]);
    }
}

// ---------------- C[M,512] = A[M,128] @ B[512,128]^T + bias0 + bias1 ----------------
__global__ __launch_bounds__(256) void k_gemm_abt(const float* __restrict__ A,
                                                   const float* __restrict__ B,
                                                   const float* __restrict__ bias0,
                                                   const float* __restrict__ bias1,
                                                   float* __restrict__ C, int M) {
    __shared__ float Alds[32 * 132];
    int tid = threadIdx.x;
    int m0 = blockIdx.x * 32;
    for (int i = tid; i < 32 * 128; i += 256) {
        int r = i >> 7;
        int k = i & 127;
        int m = m0 + r;
        Alds[r * 132 + k] = (m < M) ? A[m * 128 + k] : 0.f;
    }
    __syncthreads();
    int r = tid >> 3;
    int jb = blockIdx.y * 64 + (tid & 7) * 8;
    float acc[8];
#pragma unroll
    for (int j = 0; j < 8; j++) acc[j] = 0.f;
    const float* a_ptr = &Alds[r * 132];
#pragma unroll 8
    for (int k4 = 0; k4 < 32; ++k4) {
        float4 a = *(const float4*)(a_ptr + 4 * k4);
#pragma unroll
        for (int j = 0; j < 8; j++) {
            float4 b = *(const float4*)(B + (jb + j) * 128 + 4 * k4);
            acc[j] = fmaf(a.x, b.x, acc[j]);
            acc[j] = fmaf(a.y, b.y, acc[j]);
            acc[j] = fmaf(a.z, b.z, acc[j]);
            acc[j] = fmaf(a.w, b.w, acc[j]);
        }
    }
    int m = m0 + r;
    if (m < M) {
#pragma unroll
        for (int j = 0; j < 8; j++)
            C[m * 512 + jb + j] = acc[j] + bias0[jb + j] + bias1[jb + j];
    }
}

// ---------------- scatter: agg[dst] += h[src]*ew ----------------
__global__ void k_scatter(const float* __restrict__ h, const int* __restrict__ ei,
                          const float* __restrict__ ew, float* agg) {
    int gid = blockIdx.x * 256 + threadIdx.x;
    if (gid >= EE * 32) return;
    int e = gid >> 5;
    int q = (gid & 31) << 2;
    int src = ei[e];
    int dst = ei[EE + e];
    float w = ew[e];
    float4 v = *(const float4*)(h + src * 128 + q);
    float* p = agg + dst * 128 + q;
    atomicAdd(p + 0, v.x * w);
    atomicAdd(p + 1, v.y * w);
    atomicAdd(p + 2, v.z * w);
    atomicAdd(p + 3, v.w * w);
}

// ---------------- per-feature sum / sumsq ----------------
__global__ __launch_bounds__(256) void k_bn_stats(const float* __restrict__ x,
                                                   float* __restrict__ stats) {
    int c = threadIdx.x & 127;
    int half = threadIdx.x >> 7;
    float s = 0.f, q = 0.f;
    for (int r = blockIdx.x * 2 + half; r < NN; r += gridDim.x * 2) {
        float v = x[r * HH + c];
        s += v;
        q = fmaf(v, v, q);
    }
    __shared__ float ls[256], lq[256];
    ls[threadIdx.x] = s;
    lq[threadIdx.x] = q;
    __syncthreads();
    if (half == 0) {
        atomicAdd(&stats[c], s + ls[128 + c]);
        atomicAdd(&stats[128 + c], q + lq[128 + c]);
    }
}

// ---------------- bn + relu elementwise ----------------
__global__ void k_bn_relu(const float* __restrict__ x, const float* __restrict__ stats,
                          const float* __restrict__ g, const float* __restrict__ be,
                          float* __restrict__ out) {
    int i = blockIdx.x * 256 + threadIdx.x;
    if (i >= NN * HH) return;
    int c = i & 127;
    float mean = stats[c] * (1.f / NN);
    float var = fmaf(-mean, mean, stats[128 + c] * (1.f / NN));
    float alpha = g[c] * rsqrtf(var + 1e-5f);
    float beta = fmaf(-mean, alpha, be[c]);
    out[i] = fmaxf(0.f, fmaf(x[i], alpha, beta));
}

// ---------------- sequential bidirectional LSTM scan ----------------
// 8 waves. Wave w owns FEATURES [16w,16w+16) across ALL FOUR gate types:
// 4 M-tiles = Whh rows {0,128,256,384}+16w.., 4 K-tiles of 32. A pinned in VGPRs (bf16).
// D layout (col=lane&15, row=4*(lane>>4)+reg) => lane holds i,f,g,o for its own
// 4 features => cell update is in-register (replicated over the 16 identical cols),
// NO cross-wave gate exchange. h broadcast via double-buffered LDS, ONE barrier/step.
// xproj prefetched one step ahead (full-step load-to-use distance).
__global__ __launch_bounds__(512, 1) void k_lstm(const float* __restrict__ xpf,
                                                  const float* __restrict__ xpb,
                                                  const float* __restrict__ whf,
                                                  const float* __restrict__ whb,
                                                  float* __restrict__ hf,
                                                  float* __restrict__ hb) {
    const int dir = blockIdx.x;
    const float* __restrict__ xp = dir ? xpb : xpf;
    const float* __restrict__ Whh = dir ? whb : whf;
    float* __restrict__ hs = dir ? hb : hf;
    const int j = threadIdx.x;
    const int lane = j & 63;
    const int w = j >> 6;            // wave id -> features [16w, 16w+16)
    const int g16 = lane >> 4;       // k-group; also D row-group
    const int m = lane & 15;         // A row within tile; D col
    const int fbase = 16 * w + 4 * g16;  // this lane's 4 features

    // ---- A fragments: Whh rows 128*gt + 16*w + m, fp32 -> bf16 RNE, pinned
    short8 af[4][4];
#pragma unroll
    for (int gt = 0; gt < 4; ++gt) {
#pragma unroll
        for (int kt = 0; kt < 4; ++kt) {
            const float* wp = Whh + (128 * gt + 16 * w + m) * 128 + 32 * kt + 8 * g16;
            float4 f0 = *(const float4*)wp;
            float4 f1 = *(const float4*)(wp + 4);
            short8 a;
            a[0] = (short)f2bf(f0.x); a[1] = (short)f2bf(f0.y);
            a[2] = (short)f2bf(f0.z); a[3] = (short)f2bf(f0.w);
            a[4] = (short)f2bf(f1.x); a[5] = (short)f2bf(f1.y);
            a[6] = (short)f2bf(f1.z); a[7] = (short)f2bf(f1.w);
            af[gt][kt] = a;
        }
    }

    __shared__ __align__(16) short h_bf[2][128];   // ping-pong h broadcast
    if (j < 128) h_bf[0][j] = 0;
    f32x4 c4 = (f32x4){0.f, 0.f, 0.f, 0.f};
    __syncthreads();

    // preload xproj for first step
    int t0 = dir ? (NN - 1) : 0;
    f32x4 xq[4];
#pragma unroll
    for (int gt = 0; gt < 4; ++gt)
        xq[gt] = *(const f32x4*)(xp + t0 * G4 + 128 * gt + fbase);

    for (int step = 0; step < NN; ++step) {
        int t = dir ? (NN - 1 - step) : step;
        int sn = (step + 1 < NN) ? step + 1 : step;
        int tn = dir ? (NN - 1 - sn) : sn;

        // prefetch next step's xproj (consumed next iteration)
        f32x4 xn[4];
#pragma unroll
        for (int gt = 0; gt < 4; ++gt)
            xn[gt] = *(const f32x4*)(xp + tn * G4 + 128 * gt + fbase);

        // B fragments: h (bf16) broadcast across the 16 N columns
        const short8* hb8 = (const short8*)h_bf[step & 1];
        short8 bfr[4];
#pragma unroll
        for (int kt = 0; kt < 4; ++kt)
            bfr[kt] = hb8[4 * kt + g16];

        f32x4 acc[4];
#pragma unroll
        for (int gt = 0; gt < 4; ++gt) acc[gt] = (f32x4){0.f, 0.f, 0.f, 0.f};
#pragma unroll
        for (int kt = 0; kt < 4; ++kt) {
#pragma unroll
            for (int gt = 0; gt < 4; ++gt)
                acc[gt] = __builtin_amdgcn_mfma_f32_16x16x32_bf16(af[gt][kt], bfr[kt], acc[gt], 0, 0, 0);
        }

        // in-register cell update (replicated across 16 cols; cols identical)
        float hv[4];
#pragma unroll
        for (int r = 0; r < 4; ++r) {
            float gi = acc[0][r] + xq[0][r];
            float gf = acc[1][r] + xq[1][r];
            float gg = acc[2][r] + xq[2][r];
            float go = acc[3][r] + xq[3][r];
            float ig = sigm(gi);
            float fg = sigm(gf);
            float cg = tanh_fast(gg);
            float og = sigm(go);
            c4[r] = fmaf(fg, c4[r], ig * cg);
            hv[r] = og * tanh_fast(c4[r]);
        }

        if (m == 0) {
            *(float4*)(hs + t * HH + fbase) = make_float4(hv[0], hv[1], hv[2], hv[3]);
            short4 h4;
            h4.x = (short)f2bf(hv[0]); h4.y = (short)f2bf(hv[1]);
            h4.z = (short)f2bf(hv[2]); h4.w = (short)f2bf(hv[3]);
            *(short4*)&h_bf[(step + 1) & 1][fbase] = h4;
        }
        __syncthreads();

#pragma unroll
        for (int gt = 0; gt < 4; ++gt) xq[gt] = xn[gt];
    }
}

// ---------------- out = [hf|hb] @ Wo + bo ----------------
__global__ void k_out(const float* __restrict__ hf, const float* __restrict__ hb,
                      const float* __restrict__ Wo, const float* __restrict__ bo,
                      float* __restrict__ out) {
    int idx = blockIdx.x * 256 + threadIdx.x;
    if (idx >= NN * 12) return;
    int n = idx / 12;
    int p = idx - n * 12;
    float acc = bo[p];
    const float4* hfr = (const float4*)(hf + n * 128);
    const float4* hbr = (const float4*)(hb + n * 128);
#pragma unroll 4
    for (int k4 = 0; k4 < 32; ++k4) {
        float4 v = hfr[k4];
        acc = fmaf(v.x, Wo[(4 * k4 + 0) * 12 + p], acc);
        acc = fmaf(v.y, Wo[(4 * k4 + 1) * 12 + p], acc);
        acc = fmaf(v.z, Wo[(4 * k4 + 2) * 12 + p], acc);
        acc = fmaf(v.w, Wo[(4 * k4 + 3) * 12 + p], acc);
    }
#pragma unroll 4
    for (int k4 = 0; k4 < 32; ++k4) {
        float4 v = hbr[k4];
        acc = fmaf(v.x, Wo[(128 + 4 * k4 + 0) * 12 + p], acc);
        acc = fmaf(v.y, Wo[(128 + 4 * k4 + 1) * 12 + p], acc);
        acc = fmaf(v.z, Wo[(128 + 4 * k4 + 2) * 12 + p], acc);
        acc = fmaf(v.w, Wo[(128 + 4 * k4 + 3) * 12 + p], acc);
    }
    out[idx] = acc;
}

extern "C" void kernel_launch(void* const* d_in, const int* in_sizes, int n_in,
                              void* d_out, int out_size, void* d_ws, size_t ws_size,
                              hipStream_t stream) {
    const float* x    = (const float*)d_in[0];
    const int*   ei   = (const int*)d_in[1];
    const float* ew   = (const float*)d_in[2];
    const float* W1   = (const float*)d_in[3];
    const float* b1   = (const float*)d_in[4];
    const float* g1   = (const float*)d_in[5];
    const float* be1  = (const float*)d_in[6];
    const float* W2   = (const float*)d_in[7];
    const float* b2   = (const float*)d_in[8];
    const float* g2   = (const float*)d_in[9];
    const float* be2  = (const float*)d_in[10];
    const float* Wihf = (const float*)d_in[11];
    const float* Whhf = (const float*)d_in[12];
    const float* bihf = (const float*)d_in[13];
    const float* bhhf = (const float*)d_in[14];
    const float* Wihb = (const float*)d_in[15];
    const float* Whhb = (const float*)d_in[16];
    const float* bihb = (const float*)d_in[17];
    const float* bhhb = (const float*)d_in[18];
    const float* Wo   = (const float*)d_in[21];
    const float* bo   = (const float*)d_in[22];
    float* out = (float*)d_out;
    float* ws  = (float*)d_ws;

    float* bufA  = ws;                 // 1,280,000
    float* bufB  = ws + 1280000;       // 1,280,000
    float* bufC  = ws + 2560000;       // 1,280,000
    float* stats = ws + 3840000;       // 512
    float* Xf    = ws + 3840512;       // 5,120,000
    float* Xb    = ws + 8960512;       // 5,120,000
    float* hfp   = ws + 14080512;      // 1,280,000
    float* hbp   = ws + 15360512;      // 1,280,000

    const int nElem = NN * HH;
    const int gElem = (nElem + 255) / 256;

    k_init<<<2, 256, 0, stream>>>(stats);

    // ---- GCN layer 1 ----
    k_gemm_ab<<<313, 256, 0, stream>>>(x, W1, bufA, NN, 64, 6);
    k_bias_bcast<<<gElem, 256, 0, stream>>>(bufB, b1);
    k_scatter<<<(EE * 32) / 256, 256, 0, stream>>>(bufA, ei, ew, bufB);
    k_bn_stats<<<100, 256, 0, stream>>>(bufB, stats);
    k_bn_relu<<<gElem, 256, 0, stream>>>(bufB, stats, g1, be1, bufC);

    // ---- GCN layer 2 ----
    k_gemm_ab<<<313, 256, 0, stream>>>(bufC, W2, bufA, NN, 128, 7);
    k_bias_bcast<<<gElem, 256, 0, stream>>>(bufB, b2);
    k_scatter<<<(EE * 32) / 256, 256, 0, stream>>>(bufA, ei, ew, bufB);
    k_bn_stats<<<100, 256, 0, stream>>>(bufB, stats + 256);
    k_bn_relu<<<gElem, 256, 0, stream>>>(bufB, stats + 256, g2, be2, bufC);

    // ---- LSTM input projections (batched GEMMs, biases folded in) ----
    dim3 gx(313, 8);
    k_gemm_abt<<<gx, 256, 0, stream>>>(bufC, Wihf, bihf, bhhf, Xf, NN);
    k_gemm_abt<<<gx, 256, 0, stream>>>(bufC, Wihb, bihb, bhhb, Xb, NN);

    // ---- sequential bidirectional scan (both directions concurrent) ----
    k_lstm<<<2, 512, 0, stream>>>(Xf, Xb, Whhf, Whhb, hfp, hbp);

    // ---- attention is identity (softmax over singleton axis); final matmul ----
    k_out<<<(NN * 12 + 255) / 256, 256, 0, stream>>>(hfp, hbp, Wo, bo, out);
}

// Round 4
// 8739.997 us; speedup vs baseline: 2.6888x; 2.6888x over previous
//
#include <hip/hip_runtime.h>
#include <math.h>

#define NN 10000
#define EE 320000
#define INC 64
#define HH 128
#define G4 512

typedef short short8 __attribute__((ext_vector_type(8)));
typedef float f32x4 __attribute__((ext_vector_type(4)));

__device__ __forceinline__ float sigm(float x) { return 1.f / (1.f + __expf(-x)); }
__device__ __forceinline__ float tanh_fast(float x) { return 1.f - 2.f / (1.f + __expf(2.f * x)); }

// fp32 -> bf16 round-to-nearest-even
__device__ __forceinline__ unsigned short f2bf(float f) {
    unsigned u = __float_as_uint(f);
    unsigned r = u + 0x7FFFu + ((u >> 16) & 1u);
    return (unsigned short)(r >> 16);
}

// ---------------- init: zero bn stats (both layers) ----------------
__global__ void k_init(float* stats) {
    int i = blockIdx.x * 256 + threadIdx.x;
    if (i < 512) stats[i] = 0.f;
}

// ---------------- broadcast bias into agg buffer ----------------
__global__ void k_bias_bcast(float* __restrict__ out, const float* __restrict__ b) {
    int i = blockIdx.x * 256 + threadIdx.x;
    if (i < NN * HH) out[i] = b[i & (HH - 1)];
}

// ---------------- C[M,128] = A[M,K] @ B[K,128], K in {64,128} ----------------
__global__ __launch_bounds__(256) void k_gemm_ab(const float* __restrict__ A,
                                                 const float* __restrict__ B,
                                                 float* __restrict__ C,
                                                 int M, int K, int kshift) {
    __shared__ float Alds[32 * 129];
    int tid = threadIdx.x;
    int m0 = blockIdx.x * 32;
    for (int i = tid; i < 32 * K; i += 256) {
        int r = i >> kshift;
        int k = i & (K - 1);
        int m = m0 + r;
        Alds[r * 129 + k] = (m < M) ? A[m * K + k] : 0.f;
    }
    __syncthreads();
    int r = tid >> 3;
    int cg = (tid & 7) * 16;
    float acc[16];
#pragma unroll
    for (int j = 0; j < 16; j++) acc[j] = 0.f;
#pragma unroll 4
    for (int k = 0; k < K; ++k) {
        float a = Alds[r * 129 + k];
        const float4* Brow = (const float4*)(B + k * HH + cg);
        float4 b0 = Brow[0], b1 = Brow[1], b2 = Brow[2], b3 = Brow[3];
        acc[0]  = fmaf(a, b0.x, acc[0]);  acc[1]  = fmaf(a, b0.y, acc[1]);
        acc[2]  = fmaf(a, b0.z, acc[2]);  acc[3]  = fmaf(a, b0.w, acc[3]);
        acc[4]  = fmaf(a, b1.x, acc[4]);  acc[5]  = fmaf(a, b1.y, acc[5]);
        acc[6]  = fmaf(a, b1.z, acc[6]);  acc[7]  = fmaf(a, b1.w, acc[7]);
        acc[8]  = fmaf(a, b2.x, acc[8]);  acc[9]  = fmaf(a, b2.y, acc[9]);
        acc[10] = fmaf(a, b2.z, acc[10]); acc[11] = fmaf(a, b2.w, acc[11]);
        acc[12] = fmaf(a, b3.x, acc[12]); acc[13] = fmaf(a, b3.y, acc[13]);
        acc[14] = fmaf(a, b3.z, acc[14]); acc[15] = fmaf(a, b3.w, acc[15]);
    }
    int m = m0 + r;
    if (m < M) {
        float4* Crow = (float4*)(C + m * HH + cg);
        Crow[0] = make_float4(acc[0], acc[1], acc[2], acc[3]);
        Crow[1] = make_float4(acc[4], acc[5], acc[6], acc[7]);
        Crow[2] = make_float4(acc[8], acc[9], acc[10], acc[11]);
        Crow[3] = make_float4(acc[12], acc[13], acc[14], acc[15]);
    }
}

// ---------------- C[M,512] = A[M,128] @ B[512,128]^T + bias0 + bias1 ----------------
__global__ __launch_bounds__(256) void k_gemm_abt(const float* __restrict__ A,
                                                   const float* __restrict__ B,
                                                   const float* __restrict__ bias0,
                                                   const float* __restrict__ bias1,
                                                   float* __restrict__ C, int M) {
    __shared__ float Alds[32 * 132];
    int tid = threadIdx.x;
    int m0 = blockIdx.x * 32;
    for (int i = tid; i < 32 * 128; i += 256) {
        int r = i >> 7;
        int k = i & 127;
        int m = m0 + r;
        Alds[r * 132 + k] = (m < M) ? A[m * 128 + k] : 0.f;
    }
    __syncthreads();
    int r = tid >> 3;
    int jb = blockIdx.y * 64 + (tid & 7) * 8;
    float acc[8];
#pragma unroll
    for (int j = 0; j < 8; j++) acc[j] = 0.f;
    const float* a_ptr = &Alds[r * 132];
#pragma unroll 8
    for (int k4 = 0; k4 < 32; ++k4) {
        float4 a = *(const float4*)(a_ptr + 4 * k4);
#pragma unroll
        for (int j = 0; j < 8; j++) {
            float4 b = *(const float4*)(B + (jb + j) * 128 + 4 * k4);
            acc[j] = fmaf(a.x, b.x, acc[j]);
            acc[j] = fmaf(a.y, b.y, acc[j]);
            acc[j] = fmaf(a.z, b.z, acc[j]);
            acc[j] = fmaf(a.w, b.w, acc[j]);
        }
    }
    int m = m0 + r;
    if (m < M) {
#pragma unroll
        for (int j = 0; j < 8; j++)
            C[m * 512 + jb + j] = acc[j] + bias0[jb + j] + bias1[jb + j];
    }
}

// ---------------- scatter: agg[dst] += h[src]*ew ----------------
__global__ void k_scatter(const float* __restrict__ h, const int* __restrict__ ei,
                          const float* __restrict__ ew, float* agg) {
    int gid = blockIdx.x * 256 + threadIdx.x;
    if (gid >= EE * 32) return;
    int e = gid >> 5;
    int q = (gid & 31) << 2;
    int src = ei[e];
    int dst = ei[EE + e];
    float w = ew[e];
    float4 v = *(const float4*)(h + src * 128 + q);
    float* p = agg + dst * 128 + q;
    atomicAdd(p + 0, v.x * w);
    atomicAdd(p + 1, v.y * w);
    atomicAdd(p + 2, v.z * w);
    atomicAdd(p + 3, v.w * w);
}

// ---------------- per-feature sum / sumsq ----------------
__global__ __launch_bounds__(256) void k_bn_stats(const float* __restrict__ x,
                                                   float* __restrict__ stats) {
    int c = threadIdx.x & 127;
    int half = threadIdx.x >> 7;
    float s = 0.f, q = 0.f;
    for (int r = blockIdx.x * 2 + half; r < NN; r += gridDim.x * 2) {
        float v = x[r * HH + c];
        s += v;
        q = fmaf(v, v, q);
    }
    __shared__ float ls[256], lq[256];
    ls[threadIdx.x] = s;
    lq[threadIdx.x] = q;
    __syncthreads();
    if (half == 0) {
        atomicAdd(&stats[c], s + ls[128 + c]);
        atomicAdd(&stats[128 + c], q + lq[128 + c]);
    }
}

// ---------------- bn + relu elementwise ----------------
__global__ void k_bn_relu(const float* __restrict__ x, const float* __restrict__ stats,
                          const float* __restrict__ g, const float* __restrict__ be,
                          float* __restrict__ out) {
    int i = blockIdx.x * 256 + threadIdx.x;
    if (i >= NN * HH) return;
    int c = i & 127;
    float mean = stats[c] * (1.f / NN);
    float var = fmaf(-mean, mean, stats[128 + c] * (1.f / NN));
    float alpha = g[c] * rsqrtf(var + 1e-5f);
    float beta = fmaf(-mean, alpha, be[c]);
    out[i] = fmaxf(0.f, fmaf(x[i], alpha, beta));
}

// ---------------- sequential bidirectional LSTM scan ----------------
// 8 waves; wave w owns features [16w,16w+16) across all 4 gate types (tiles = gate
// rows {0,128,256,384}+16w..). A (Whh bf16) pinned in VGPRs. D layout (col=lane&15,
// row=4*(lane>>4)+reg): lane (g16,m) holds gates of features 16w+4g16+{0..3}.
// Each lane then SELECTS reg (m&3) -> processes EXACTLY ONE feature (4x redundant
// across m-groups) => per-wave issue = one activation chain (10 trans), not four
// (R3 lesson: exec masks don't reduce issue; replication is paid in trans issue).
// One barrier/step (ping-pong h_bf), lgkm-only drain so xproj loads (2-step
// prefetch) stay in flight across barriers.
__global__ __launch_bounds__(512, 1) void k_lstm(const float* __restrict__ xpf,
                                                  const float* __restrict__ xpb,
                                                  const float* __restrict__ whf,
                                                  const float* __restrict__ whb,
                                                  float* __restrict__ hf,
                                                  float* __restrict__ hb) {
    const int dir = blockIdx.x;
    const float* __restrict__ xp = dir ? xpb : xpf;
    const float* __restrict__ Whh = dir ? whb : whf;
    float* __restrict__ hs = dir ? hb : hf;
    const int j = threadIdx.x;
    const int lane = j & 63;
    const int w = j >> 6;            // wave id -> features [16w, 16w+16)
    const int g16 = lane >> 4;       // k-group; also D row-group
    const int m = lane & 15;         // A row within tile; D col
    const int r2 = m & 3;            // which acc reg = this lane's feature
    const int f1 = 16 * w + 4 * g16 + r2;   // this lane's single feature
    const bool writer = (m < 4);     // one writer per (g16, r2) combo

    // ---- A fragments: Whh rows 128*gt + 16*w + m, fp32 -> bf16 RNE, pinned
    short8 af[4][4];
#pragma unroll
    for (int gt = 0; gt < 4; ++gt) {
#pragma unroll
        for (int kt = 0; kt < 4; ++kt) {
            const float* wp = Whh + (128 * gt + 16 * w + m) * 128 + 32 * kt + 8 * g16;
            float4 f0 = *(const float4*)wp;
            float4 f1v = *(const float4*)(wp + 4);
            short8 a;
            a[0] = (short)f2bf(f0.x); a[1] = (short)f2bf(f0.y);
            a[2] = (short)f2bf(f0.z); a[3] = (short)f2bf(f0.w);
            a[4] = (short)f2bf(f1v.x); a[5] = (short)f2bf(f1v.y);
            a[6] = (short)f2bf(f1v.z); a[7] = (short)f2bf(f1v.w);
            af[gt][kt] = a;
        }
    }

    __shared__ __align__(16) short h_bf[2][128];   // ping-pong h broadcast
    if (j < 128) h_bf[0][j] = 0;
    float c = 0.f;
    __syncthreads();

    // xproj prefetch, depth 2 (per-lane scalar loads for its feature's 4 gates)
    int ta = dir ? (NN - 1) : 0;
    int tb = dir ? (NN - 2) : 1;
    float x0[4], x1[4];
#pragma unroll
    for (int gt = 0; gt < 4; ++gt) x0[gt] = xp[ta * G4 + 128 * gt + f1];
#pragma unroll
    for (int gt = 0; gt < 4; ++gt) x1[gt] = xp[tb * G4 + 128 * gt + f1];

    for (int step = 0; step < NN; ++step) {
        int t = dir ? (NN - 1 - step) : step;
        int s2 = (step + 2 < NN) ? step + 2 : NN - 1;
        int t2 = dir ? (NN - 1 - s2) : s2;

        // issue prefetch for step+2 (consumed 2 steps later; rides across barriers)
        float x2[4];
#pragma unroll
        for (int gt = 0; gt < 4; ++gt) x2[gt] = xp[t2 * G4 + 128 * gt + f1];

        // B fragments: h (bf16) broadcast across the 16 N columns
        const short8* hb8 = (const short8*)h_bf[step & 1];
        short8 bfr[4];
#pragma unroll
        for (int kt = 0; kt < 4; ++kt)
            bfr[kt] = hb8[4 * kt + g16];

        f32x4 acc[4];
#pragma unroll
        for (int gt = 0; gt < 4; ++gt) acc[gt] = (f32x4){0.f, 0.f, 0.f, 0.f};
#pragma unroll
        for (int kt = 0; kt < 4; ++kt) {
#pragma unroll
            for (int gt = 0; gt < 4; ++gt)
                acc[gt] = __builtin_amdgcn_mfma_f32_16x16x32_bf16(af[gt][kt], bfr[kt], acc[gt], 0, 0, 0);
        }

        // select reg r2 of each gate tile -> this lane's 4 gate pre-activations
        float gv[4];
#pragma unroll
        for (int gt = 0; gt < 4; ++gt) {
            float lo = (r2 & 1) ? acc[gt][1] : acc[gt][0];
            float hi = (r2 & 1) ? acc[gt][3] : acc[gt][2];
            gv[gt] = (r2 & 2) ? hi : lo;
        }

        // single-feature cell update (4x redundant across m-groups; identical values)
        float gi = gv[0] + x0[0];
        float gf = gv[1] + x0[1];
        float gg = gv[2] + x0[2];
        float go = gv[3] + x0[3];
        float ig = sigm(gi);
        float fg = sigm(gf);
        float cg = tanh_fast(gg);
        float og = sigm(go);
        c = fmaf(fg, c, ig * cg);
        float h = og * tanh_fast(c);

        if (writer) {
            hs[t * HH + f1] = h;
            h_bf[(step + 1) & 1][f1] = (short)f2bf(h);
        }
        // lgkm-only drain: LDS h visible to all waves, but VMEM loads stay in flight
        asm volatile("s_waitcnt lgkmcnt(0)\n\ts_barrier" ::: "memory");

#pragma unroll
        for (int gt = 0; gt < 4; ++gt) { x0[gt] = x1[gt]; x1[gt] = x2[gt]; }
    }
}

// ---------------- out = [hf|hb] @ Wo + bo ----------------
__global__ void k_out(const float* __restrict__ hf, const float* __restrict__ hb,
                      const float* __restrict__ Wo, const float* __restrict__ bo,
                      float* __restrict__ out) {
    int idx = blockIdx.x * 256 + threadIdx.x;
    if (idx >= NN * 12) return;
    int n = idx / 12;
    int p = idx - n * 12;
    float acc = bo[p];
    const float4* hfr = (const float4*)(hf + n * 128);
    const float4* hbr = (const float4*)(hb + n * 128);
#pragma unroll 4
    for (int k4 = 0; k4 < 32; ++k4) {
        float4 v = hfr[k4];
        acc = fmaf(v.x, Wo[(4 * k4 + 0) * 12 + p], acc);
        acc = fmaf(v.y, Wo[(4 * k4 + 1) * 12 + p], acc);
        acc = fmaf(v.z, Wo[(4 * k4 + 2) * 12 + p], acc);
        acc = fmaf(v.w, Wo[(4 * k4 + 3) * 12 + p], acc);
    }
#pragma unroll 4
    for (int k4 = 0; k4 < 32; ++k4) {
        float4 v = hbr[k4];
        acc = fmaf(v.x, Wo[(128 + 4 * k4 + 0) * 12 + p], acc);
        acc = fmaf(v.y, Wo[(128 + 4 * k4 + 1) * 12 + p], acc);
        acc = fmaf(v.z, Wo[(128 + 4 * k4 + 2) * 12 + p], acc);
        acc = fmaf(v.w, Wo[(128 + 4 * k4 + 3) * 12 + p], acc);
    }
    out[idx] = acc;
}

extern "C" void kernel_launch(void* const* d_in, const int* in_sizes, int n_in,
                              void* d_out, int out_size, void* d_ws, size_t ws_size,
                              hipStream_t stream) {
    const float* x    = (const float*)d_in[0];
    const int*   ei   = (const int*)d_in[1];
    const float* ew   = (const float*)d_in[2];
    const float* W1   = (const float*)d_in[3];
    const float* b1   = (const float*)d_in[4];
    const float* g1   = (const float*)d_in[5];
    const float* be1  = (const float*)d_in[6];
    const float* W2   = (const float*)d_in[7];
    const float* b2   = (const float*)d_in[8];
    const float* g2   = (const float*)d_in[9];
    const float* be2  = (const float*)d_in[10];
    const float* Wihf = (const float*)d_in[11];
    const float* Whhf = (const float*)d_in[12];
    const float* bihf = (const float*)d_in[13];
    const float* bhhf = (const float*)d_in[14];
    const float* Wihb = (const float*)d_in[15];
    const float* Whhb = (const float*)d_in[16];
    const float* bihb = (const float*)d_in[17];
    const float* bhhb = (const float*)d_in[18];
    const float* Wo   = (const float*)d_in[21];
    const float* bo   = (const float*)d_in[22];
    float* out = (float*)d_out;
    float* ws  = (float*)d_ws;

    float* bufA  = ws;                 // 1,280,000
    float* bufB  = ws + 1280000;       // 1,280,000
    float* bufC  = ws + 2560000;       // 1,280,000
    float* stats = ws + 3840000;       // 512
    float* Xf    = ws + 3840512;       // 5,120,000
    float* Xb    = ws + 8960512;       // 5,120,000
    float* hfp   = ws + 14080512;      // 1,280,000
    float* hbp   = ws + 15360512;      // 1,280,000

    const int nElem = NN * HH;
    const int gElem = (nElem + 255) / 256;

    k_init<<<2, 256, 0, stream>>>(stats);

    // ---- GCN layer 1 ----
    k_gemm_ab<<<313, 256, 0, stream>>>(x, W1, bufA, NN, 64, 6);
    k_bias_bcast<<<gElem, 256, 0, stream>>>(bufB, b1);
    k_scatter<<<(EE * 32) / 256, 256, 0, stream>>>(bufA, ei, ew, bufB);
    k_bn_stats<<<100, 256, 0, stream>>>(bufB, stats);
    k_bn_relu<<<gElem, 256, 0, stream>>>(bufB, stats, g1, be1, bufC);

    // ---- GCN layer 2 ----
    k_gemm_ab<<<313, 256, 0, stream>>>(bufC, W2, bufA, NN, 128, 7);
    k_bias_bcast<<<gElem, 256, 0, stream>>>(bufB, b2);
    k_scatter<<<(EE * 32) / 256, 256, 0, stream>>>(bufA, ei, ew, bufB);
    k_bn_stats<<<100, 256, 0, stream>>>(bufB, stats + 256);
    k_bn_relu<<<gElem, 256, 0, stream>>>(bufB, stats + 256, g2, be2, bufC);

    // ---- LSTM input projections (batched GEMMs, biases folded in) ----
    dim3 gx(313, 8);
    k_gemm_abt<<<gx, 256, 0, stream>>>(bufC, Wihf, bihf, bhhf, Xf, NN);
    k_gemm_abt<<<gx, 256, 0, stream>>>(bufC, Wihb, bihb, bhhb, Xb, NN);

    // ---- sequential bidirectional scan (both directions concurrent) ----
    k_lstm<<<2, 512, 0, stream>>>(Xf, Xb, Whhf, Whhb, hfp, hbp);

    // ---- attention is identity (softmax over singleton axis); final matmul ----
    k_out<<<(NN * 12 + 255) / 256, 256, 0, stream>>>(hfp, hbp, Wo, bo, out);
}

// Round 5
// 7916.148 us; speedup vs baseline: 2.9686x; 1.1041x over previous
//
#include <hip/hip_runtime.h>
#include <math.h>

#define NN 10000
#define EE 320000
#define INC 64
#define HH 128
#define G4 512

typedef short short8 __attribute__((ext_vector_type(8)));
typedef float f32x4 __attribute__((ext_vector_type(4)));

__device__ __forceinline__ float sigm(float x) { return 1.f / (1.f + __expf(-x)); }
__device__ __forceinline__ float tanh_fast(float x) { return 1.f - 2.f / (1.f + __expf(2.f * x)); }

// fp32 -> bf16 round-to-nearest-even
__device__ __forceinline__ unsigned short f2bf(float f) {
    unsigned u = __float_as_uint(f);
    unsigned r = u + 0x7FFFu + ((u >> 16) & 1u);
    return (unsigned short)(r >> 16);
}

// ---------------- init: zero bn stats (both layers) ----------------
__global__ void k_init(float* stats) {
    int i = blockIdx.x * 256 + threadIdx.x;
    if (i < 512) stats[i] = 0.f;
}

// ---------------- broadcast bias into agg buffer ----------------
__global__ void k_bias_bcast(float* __restrict__ out, const float* __restrict__ b) {
    int i = blockIdx.x * 256 + threadIdx.x;
    if (i < NN * HH) out[i] = b[i & (HH - 1)];
}

// ---------------- C[M,128] = A[M,K] @ B[K,128], K in {64,128} ----------------
__global__ __launch_bounds__(256) void k_gemm_ab(const float* __restrict__ A,
                                                 const float* __restrict__ B,
                                                 float* __restrict__ C,
                                                 int M, int K, int kshift) {
    __shared__ float Alds[32 * 129];
    int tid = threadIdx.x;
    int m0 = blockIdx.x * 32;
    for (int i = tid; i < 32 * K; i += 256) {
        int r = i >> kshift;
        int k = i & (K - 1);
        int m = m0 + r;
        Alds[r * 129 + k] = (m < M) ? A[m * K + k] : 0.f;
    }
    __syncthreads();
    int r = tid >> 3;
    int cg = (tid & 7) * 16;
    float acc[16];
#pragma unroll
    for (int j = 0; j < 16; j++) acc[j] = 0.f;
#pragma unroll 4
    for (int k = 0; k < K; ++k) {
        float a = Alds[r * 129 + k];
        const float4* Brow = (const float4*)(B + k * HH + cg);
        float4 b0 = Brow[0], b1 = Brow[1], b2 = Brow[2], b3 = Brow[3];
        acc[0]  = fmaf(a, b0.x, acc[0]);  acc[1]  = fmaf(a, b0.y, acc[1]);
        acc[2]  = fmaf(a, b0.z, acc[2]);  acc[3]  = fmaf(a, b0.w, acc[3]);
        acc[4]  = fmaf(a, b1.x, acc[4]);  acc[5]  = fmaf(a, b1.y, acc[5]);
        acc[6]  = fmaf(a, b1.z, acc[6]);  acc[7]  = fmaf(a, b1.w, acc[7]);
        acc[8]  = fmaf(a, b2.x, acc[8]);  acc[9]  = fmaf(a, b2.y, acc[9]);
        acc[10] = fmaf(a, b2.z, acc[10]); acc[11] = fmaf(a, b2.w, acc[11]);
        acc[12] = fmaf(a, b3.x, acc[12]); acc[13] = fmaf(a, b3.y, acc[13]);
        acc[14] = fmaf(a, b3.z, acc[14]); acc[15] = fmaf(a, b3.w, acc[15]);
    }
    int m = m0 + r;
    if (m < M) {
        float4* Crow = (float4*)(C + m * HH + cg);
        Crow[0] = make_float4(acc[0], acc[1], acc[2], acc[3]);
        Crow[1] = make_float4(acc[4], acc[5], acc[6], acc[7]);
        Crow[2] = make_float4(acc[8], acc[9], acc[10], acc[11]);
        Crow[3] = make_float4(acc[12], acc[13], acc[14], acc[15]);
    }
}

// ---------------- X[M][128 feat][4 gate] = A[M,128] @ B[512,128]^T + biases ----------------
// Permuted output layout: lane in k_lstm reads its feature's 4 gates as ONE float4.
// Each thread computes 2 features x 4 gates -> two coalesced float4 stores.
__global__ __launch_bounds__(256) void k_gemm_abt(const float* __restrict__ A,
                                                   const float* __restrict__ B,
                                                   const float* __restrict__ bias0,
                                                   const float* __restrict__ bias1,
                                                   float* __restrict__ C, int M) {
    __shared__ float Alds[32 * 132];
    int tid = threadIdx.x;
    int m0 = blockIdx.x * 32;
    for (int i = tid; i < 32 * 128; i += 256) {
        int r = i >> 7;
        int k = i & 127;
        int m = m0 + r;
        Alds[r * 132 + k] = (m < M) ? A[m * 128 + k] : 0.f;
    }
    __syncthreads();
    int r = tid >> 3;
    int f0 = blockIdx.y * 16 + (tid & 7) * 2;   // 2 features per thread
    float acc[2][4];
#pragma unroll
    for (int fi = 0; fi < 2; fi++)
#pragma unroll
        for (int gt = 0; gt < 4; gt++) acc[fi][gt] = 0.f;
    const float* a_ptr = &Alds[r * 132];
#pragma unroll 8
    for (int k4 = 0; k4 < 32; ++k4) {
        float4 a = *(const float4*)(a_ptr + 4 * k4);
#pragma unroll
        for (int fi = 0; fi < 2; fi++) {
#pragma unroll
            for (int gt = 0; gt < 4; gt++) {
                float4 b = *(const float4*)(B + (128 * gt + f0 + fi) * 128 + 4 * k4);
                acc[fi][gt] = fmaf(a.x, b.x, acc[fi][gt]);
                acc[fi][gt] = fmaf(a.y, b.y, acc[fi][gt]);
                acc[fi][gt] = fmaf(a.z, b.z, acc[fi][gt]);
                acc[fi][gt] = fmaf(a.w, b.w, acc[fi][gt]);
            }
        }
    }
    int m = m0 + r;
    if (m < M) {
#pragma unroll
        for (int fi = 0; fi < 2; fi++) {
            int f = f0 + fi;
            float4 v;
            v.x = acc[fi][0] + bias0[f]       + bias1[f];
            v.y = acc[fi][1] + bias0[128 + f] + bias1[128 + f];
            v.z = acc[fi][2] + bias0[256 + f] + bias1[256 + f];
            v.w = acc[fi][3] + bias0[384 + f] + bias1[384 + f];
            *(float4*)(C + m * 512 + f * 4) = v;
        }
    }
}

// ---------------- scatter: agg[dst] += h[src]*ew ----------------
__global__ void k_scatter(const float* __restrict__ h, const int* __restrict__ ei,
                          const float* __restrict__ ew, float* agg) {
    int gid = blockIdx.x * 256 + threadIdx.x;
    if (gid >= EE * 32) return;
    int e = gid >> 5;
    int q = (gid & 31) << 2;
    int src = ei[e];
    int dst = ei[EE + e];
    float w = ew[e];
    float4 v = *(const float4*)(h + src * 128 + q);
    float* p = agg + dst * 128 + q;
    atomicAdd(p + 0, v.x * w);
    atomicAdd(p + 1, v.y * w);
    atomicAdd(p + 2, v.z * w);
    atomicAdd(p + 3, v.w * w);
}

// ---------------- per-feature sum / sumsq ----------------
__global__ __launch_bounds__(256) void k_bn_stats(const float* __restrict__ x,
                                                   float* __restrict__ stats) {
    int c = threadIdx.x & 127;
    int half = threadIdx.x >> 7;
    float s = 0.f, q = 0.f;
    for (int r = blockIdx.x * 2 + half; r < NN; r += gridDim.x * 2) {
        float v = x[r * HH + c];
        s += v;
        q = fmaf(v, v, q);
    }
    __shared__ float ls[256], lq[256];
    ls[threadIdx.x] = s;
    lq[threadIdx.x] = q;
    __syncthreads();
    if (half == 0) {
        atomicAdd(&stats[c], s + ls[128 + c]);
        atomicAdd(&stats[128 + c], q + lq[128 + c]);
    }
}

// ---------------- bn + relu elementwise ----------------
__global__ void k_bn_relu(const float* __restrict__ x, const float* __restrict__ stats,
                          const float* __restrict__ g, const float* __restrict__ be,
                          float* __restrict__ out) {
    int i = blockIdx.x * 256 + threadIdx.x;
    if (i >= NN * HH) return;
    int c = i & 127;
    float mean = stats[c] * (1.f / NN);
    float var = fmaf(-mean, mean, stats[128 + c] * (1.f / NN));
    float alpha = g[c] * rsqrtf(var + 1e-5f);
    float beta = fmaf(-mean, alpha, be[c]);
    out[i] = fmaxf(0.f, fmaf(x[i], alpha, beta));
}

// ---------------- sequential bidirectional LSTM scan ----------------
// R4 structure (one feature per lane, one lgkm-barrier/step) with issue-count cuts:
// (1) xproj in [t][f][gate] layout -> ONE dwordx4 per lane per step;
// (2) walking pointers, no per-step t/clamp arithmetic (tail prefetch overruns
//     land in adjacent ws buffers, values never consumed);
// (3) 2x unrolled loop: h_bf ping-pong fully static.
__global__ __launch_bounds__(512, 1) void k_lstm(const float* __restrict__ xpf,
                                                  const float* __restrict__ xpb,
                                                  const float* __restrict__ whf,
                                                  const float* __restrict__ whb,
                                                  float* __restrict__ hf,
                                                  float* __restrict__ hb) {
    const int dir = blockIdx.x;
    const float* __restrict__ xp = dir ? xpb : xpf;
    const float* __restrict__ Whh = dir ? whb : whf;
    float* __restrict__ hsp = dir ? hb : hf;
    const int j = threadIdx.x;
    const int lane = j & 63;
    const int w = j >> 6;            // wave id -> features [16w, 16w+16)
    const int g16 = lane >> 4;       // k-group; D row-group
    const int m = lane & 15;         // A row within tile; D col
    const int r2 = m & 3;            // acc reg = this lane's feature
    const int f1 = 16 * w + 4 * g16 + r2;
    const bool writer = (m < 4);

    // ---- A fragments: Whh rows 128*gt + 16*w + m, fp32 -> bf16 RNE, pinned
    short8 af[4][4];
#pragma unroll
    for (int gt = 0; gt < 4; ++gt) {
#pragma unroll
        for (int kt = 0; kt < 4; ++kt) {
            const float* wp = Whh + (128 * gt + 16 * w + m) * 128 + 32 * kt + 8 * g16;
            float4 q0 = *(const float4*)wp;
            float4 q1 = *(const float4*)(wp + 4);
            short8 a;
            a[0] = (short)f2bf(q0.x); a[1] = (short)f2bf(q0.y);
            a[2] = (short)f2bf(q0.z); a[3] = (short)f2bf(q0.w);
            a[4] = (short)f2bf(q1.x); a[5] = (short)f2bf(q1.y);
            a[6] = (short)f2bf(q1.z); a[7] = (short)f2bf(q1.w);
            af[gt][kt] = a;
        }
    }

    __shared__ __align__(16) short h_bf[2][128];
    if (j < 128) h_bf[0][j] = 0;
    float c = 0.f;
    __syncthreads();

    // walking pointers (per-lane)
    const int xinc = dir ? -G4 : G4;          // floats per step
    const int hinc = dir ? -HH : HH;
    const float* xptr = xp + (dir ? (NN - 1) : 0) * G4 + f1 * 4;
    float* hptr = hsp + (dir ? (NN - 1) : 0) * HH + f1;

    // preload xproj for steps 0,1; xptr then points at step 2
    f32x4 xE = *(const f32x4*)xptr; xptr += xinc;
    f32x4 xO = *(const f32x4*)xptr; xptr += xinc;

    for (int s = 0; s < NN; s += 2) {
        // ================= even step =================
        f32x4 xE2 = *(const f32x4*)xptr; xptr += xinc;   // for s+2
        {
            const short8* hb8 = (const short8*)h_bf[0];
            short8 b0 = hb8[g16], b1 = hb8[4 + g16], b2 = hb8[8 + g16], b3 = hb8[12 + g16];
            f32x4 acc[4];
#pragma unroll
            for (int gt = 0; gt < 4; ++gt) acc[gt] = (f32x4){0.f, 0.f, 0.f, 0.f};
#pragma unroll
            for (int gt = 0; gt < 4; ++gt) acc[gt] = __builtin_amdgcn_mfma_f32_16x16x32_bf16(af[gt][0], b0, acc[gt], 0, 0, 0);
#pragma unroll
            for (int gt = 0; gt < 4; ++gt) acc[gt] = __builtin_amdgcn_mfma_f32_16x16x32_bf16(af[gt][1], b1, acc[gt], 0, 0, 0);
#pragma unroll
            for (int gt = 0; gt < 4; ++gt) acc[gt] = __builtin_amdgcn_mfma_f32_16x16x32_bf16(af[gt][2], b2, acc[gt], 0, 0, 0);
#pragma unroll
            for (int gt = 0; gt < 4; ++gt) acc[gt] = __builtin_amdgcn_mfma_f32_16x16x32_bf16(af[gt][3], b3, acc[gt], 0, 0, 0);

            float gv[4];
#pragma unroll
            for (int gt = 0; gt < 4; ++gt) {
                float lo = (r2 & 1) ? acc[gt][1] : acc[gt][0];
                float hi = (r2 & 1) ? acc[gt][3] : acc[gt][2];
                gv[gt] = (r2 & 2) ? hi : lo;
            }
            float ig = sigm(gv[0] + xE[0]);
            float fg = sigm(gv[1] + xE[1]);
            float cg = tanh_fast(gv[2] + xE[2]);
            float og = sigm(gv[3] + xE[3]);
            c = fmaf(fg, c, ig * cg);
            float h = og * tanh_fast(c);
            if (writer) {
                *hptr = h;
                h_bf[1][f1] = (short)f2bf(h);
            }
            hptr += hinc;
        }
        asm volatile("s_waitcnt lgkmcnt(0)\n\ts_barrier" ::: "memory");

        // ================= odd step =================
        f32x4 xO2 = *(const f32x4*)xptr; xptr += xinc;   // for s+3
        {
            const short8* hb8 = (const short8*)h_bf[1];
            short8 b0 = hb8[g16], b1 = hb8[4 + g16], b2 = hb8[8 + g16], b3 = hb8[12 + g16];
            f32x4 acc[4];
#pragma unroll
            for (int gt = 0; gt < 4; ++gt) acc[gt] = (f32x4){0.f, 0.f, 0.f, 0.f};
#pragma unroll
            for (int gt = 0; gt < 4; ++gt) acc[gt] = __builtin_amdgcn_mfma_f32_16x16x32_bf16(af[gt][0], b0, acc[gt], 0, 0, 0);
#pragma unroll
            for (int gt = 0; gt < 4; ++gt) acc[gt] = __builtin_amdgcn_mfma_f32_16x16x32_bf16(af[gt][1], b1, acc[gt], 0, 0, 0);
#pragma unroll
            for (int gt = 0; gt < 4; ++gt) acc[gt] = __builtin_amdgcn_mfma_f32_16x16x32_bf16(af[gt][2], b2, acc[gt], 0, 0, 0);
#pragma unroll
            for (int gt = 0; gt < 4; ++gt) acc[gt] = __builtin_amdgcn_mfma_f32_16x16x32_bf16(af[gt][3], b3, acc[gt], 0, 0, 0);

            float gv[4];
#pragma unroll
            for (int gt = 0; gt < 4; ++gt) {
                float lo = (r2 & 1) ? acc[gt][1] : acc[gt][0];
                float hi = (r2 & 1) ? acc[gt][3] : acc[gt][2];
                gv[gt] = (r2 & 2) ? hi : lo;
            }
            float ig = sigm(gv[0] + xO[0]);
            float fg = sigm(gv[1] + xO[1]);
            float cg = tanh_fast(gv[2] + xO[2]);
            float og = sigm(gv[3] + xO[3]);
            c = fmaf(fg, c, ig * cg);
            float h = og * tanh_fast(c);
            if (writer) {
                *hptr = h;
                h_bf[0][f1] = (short)f2bf(h);
            }
            hptr += hinc;
        }
        asm volatile("s_waitcnt lgkmcnt(0)\n\ts_barrier" ::: "memory");

        xE = xE2;
        xO = xO2;
    }
}

// ---------------- out = [hf|hb] @ Wo + bo ----------------
__global__ void k_out(const float* __restrict__ hf, const float* __restrict__ hb,
                      const float* __restrict__ Wo, const float* __restrict__ bo,
                      float* __restrict__ out) {
    int idx = blockIdx.x * 256 + threadIdx.x;
    if (idx >= NN * 12) return;
    int n = idx / 12;
    int p = idx - n * 12;
    float acc = bo[p];
    const float4* hfr = (const float4*)(hf + n * 128);
    const float4* hbr = (const float4*)(hb + n * 128);
#pragma unroll 4
    for (int k4 = 0; k4 < 32; ++k4) {
        float4 v = hfr[k4];
        acc = fmaf(v.x, Wo[(4 * k4 + 0) * 12 + p], acc);
        acc = fmaf(v.y, Wo[(4 * k4 + 1) * 12 + p], acc);
        acc = fmaf(v.z, Wo[(4 * k4 + 2) * 12 + p], acc);
        acc = fmaf(v.w, Wo[(4 * k4 + 3) * 12 + p], acc);
    }
#pragma unroll 4
    for (int k4 = 0; k4 < 32; ++k4) {
        float4 v = hbr[k4];
        acc = fmaf(v.x, Wo[(128 + 4 * k4 + 0) * 12 + p], acc);
        acc = fmaf(v.y, Wo[(128 + 4 * k4 + 1) * 12 + p], acc);
        acc = fmaf(v.z, Wo[(128 + 4 * k4 + 2) * 12 + p], acc);
        acc = fmaf(v.w, Wo[(128 + 4 * k4 + 3) * 12 + p], acc);
    }
    out[idx] = acc;
}

extern "C" void kernel_launch(void* const* d_in, const int* in_sizes, int n_in,
                              void* d_out, int out_size, void* d_ws, size_t ws_size,
                              hipStream_t stream) {
    const float* x    = (const float*)d_in[0];
    const int*   ei   = (const int*)d_in[1];
    const float* ew   = (const float*)d_in[2];
    const float* W1   = (const float*)d_in[3];
    const float* b1   = (const float*)d_in[4];
    const float* g1   = (const float*)d_in[5];
    const float* be1  = (const float*)d_in[6];
    const float* W2   = (const float*)d_in[7];
    const float* b2   = (const float*)d_in[8];
    const float* g2   = (const float*)d_in[9];
    const float* be2  = (const float*)d_in[10];
    const float* Wihf = (const float*)d_in[11];
    const float* Whhf = (const float*)d_in[12];
    const float* bihf = (const float*)d_in[13];
    const float* bhhf = (const float*)d_in[14];
    const float* Wihb = (const float*)d_in[15];
    const float* Whhb = (const float*)d_in[16];
    const float* bihb = (const float*)d_in[17];
    const float* bhhb = (const float*)d_in[18];
    const float* Wo   = (const float*)d_in[21];
    const float* bo   = (const float*)d_in[22];
    float* out = (float*)d_out;
    float* ws  = (float*)d_ws;

    float* bufA  = ws;                 // 1,280,000
    float* bufB  = ws + 1280000;       // 1,280,000
    float* bufC  = ws + 2560000;       // 1,280,000
    float* stats = ws + 3840000;       // 512
    float* Xf    = ws + 3840512;       // 5,120,000
    float* Xb    = ws + 8960512;       // 5,120,000
    float* hfp   = ws + 14080512;      // 1,280,000
    float* hbp   = ws + 15360512;      // 1,280,000

    const int nElem = NN * HH;
    const int gElem = (nElem + 255) / 256;

    k_init<<<2, 256, 0, stream>>>(stats);

    // ---- GCN layer 1 ----
    k_gemm_ab<<<313, 256, 0, stream>>>(x, W1, bufA, NN, 64, 6);
    k_bias_bcast<<<gElem, 256, 0, stream>>>(bufB, b1);
    k_scatter<<<(EE * 32) / 256, 256, 0, stream>>>(bufA, ei, ew, bufB);
    k_bn_stats<<<100, 256, 0, stream>>>(bufB, stats);
    k_bn_relu<<<gElem, 256, 0, stream>>>(bufB, stats, g1, be1, bufC);

    // ---- GCN layer 2 ----
    k_gemm_ab<<<313, 256, 0, stream>>>(bufC, W2, bufA, NN, 128, 7);
    k_bias_bcast<<<gElem, 256, 0, stream>>>(bufB, b2);
    k_scatter<<<(EE * 32) / 256, 256, 0, stream>>>(bufA, ei, ew, bufB);
    k_bn_stats<<<100, 256, 0, stream>>>(bufB, stats + 256);
    k_bn_relu<<<gElem, 256, 0, stream>>>(bufB, stats + 256, g2, be2, bufC);

    // ---- LSTM input projections (batched GEMMs, biases folded, permuted layout) ----
    dim3 gx(313, 8);
    k_gemm_abt<<<gx, 256, 0, stream>>>(bufC, Wihf, bihf, bhhf, Xf, NN);
    k_gemm_abt<<<gx, 256, 0, stream>>>(bufC, Wihb, bihb, bhhb, Xb, NN);

    // ---- sequential bidirectional scan (both directions concurrent) ----
    k_lstm<<<2, 512, 0, stream>>>(Xf, Xb, Whhf, Whhb, hfp, hbp);

    // ---- attention is identity (softmax over singleton axis); final matmul ----
    k_out<<<(NN * 12 + 255) / 256, 256, 0, stream>>>(hfp, hbp, Wo, bo, out);
}